// Round 1
// baseline (230.044 us; speedup 1.0000x reference)
//
#include <hip/hip_runtime.h>

// ---------------------------------------------------------------------------
// MultiHeadedAttention: x[8,1024,768] @ w_in[768,2304] -> qkv -> 12-head attn
// (scale = 768^-0.5) -> concat -> @ w_out[768,768] + b_out. f32 in/out,
// bf16 MFMA internally (threshold is 2% of max|ref|).
// ---------------------------------------------------------------------------

using short8 = __attribute__((ext_vector_type(8))) short;  // 8 bf16 (4 VGPR)
using f32x4  = __attribute__((ext_vector_type(4))) float;  // MFMA acc

#define MFMA_B16(a, b, c) __builtin_amdgcn_mfma_f32_16x16x32_bf16((a), (b), (c), 0, 0, 0)

constexpr int   kDim   = 768;
constexpr int   kHeads = 12;
constexpr int   kSeq   = 1024;
constexpr float kScale = 0.03608439182435161f;  // 768^-0.5 (full dim, per ref)

__device__ __forceinline__ short f2bf(float f) {  // RNE f32 -> bf16 bits
  unsigned u = __float_as_uint(f);
  u += 0x7FFFu + ((u >> 16) & 1u);
  return (short)(u >> 16);
}

// ---------- transpose + convert: out[c][r] = bf16(in[r][c]) ----------------
__global__ __launch_bounds__(256) void transpose_cvt(const float* __restrict__ in,
                                                     short* __restrict__ out,
                                                     int R, int C) {
  __shared__ float tile[32][33];
  const int c0 = blockIdx.x * 32, r0 = blockIdx.y * 32;
  const int tx = threadIdx.x & 31, ty = threadIdx.x >> 5;  // 256 thr: ty 0..7
#pragma unroll
  for (int i = 0; i < 32; i += 8)
    tile[ty + i][tx] = in[(size_t)(r0 + ty + i) * C + c0 + tx];
  __syncthreads();
#pragma unroll
  for (int i = 0; i < 32; i += 8)
    out[(size_t)(c0 + ty + i) * R + r0 + tx] = f2bf(tile[tx][ty + i]);
}

// ---------- 128x128 MFMA GEMM, BK=32, 4 waves ------------------------------
// A: [M][K]  (AMODE 0: f32 source, converted while staging; 1: bf16/short)
// B: given transposed BT[n][k] (bf16) so B-fragments read 16B contiguous.
// EPI 0: scatter qkv tile to Q[bh][n][d], K[bh][n][d], VT[bh][d][n]
// EPI 1: out[m][n] = acc + bias[n]  (f32)
template <int AMODE, int EPI>
__global__ __launch_bounds__(256) void gemm_tile(const void* __restrict__ Aptr,
                                                 const short* __restrict__ BT,
                                                 int Kd,
                                                 short* __restrict__ Qb,
                                                 short* __restrict__ Kb,
                                                 short* __restrict__ VTb,
                                                 const float* __restrict__ bias,
                                                 float* __restrict__ outF) {
  // pitch 40 bf16 = 80 B (16B-aligned rows; (5r+g)&7 is a permutation -> no
  // systematic bank-quad pileup on ds_read_b128)
  __shared__ short As[128 * 40];
  __shared__ short Bs[128 * 40];

  const int tid  = threadIdx.x;
  const int lane = tid & 63, w = tid >> 6;
  const int L = lane & 15, g = lane >> 4;
  const int wr = w >> 1, wc = w & 1;
  const int m0 = blockIdx.x * 128, n0 = blockIdx.y * 128;

  const int arow = tid >> 1;            // 0..127
  const int ac0  = (tid & 1) * 16;      // 0 or 16

  f32x4 acc[4][4] = {};

  for (int k0 = 0; k0 < Kd; k0 += 32) {
    __syncthreads();
    // ---- stage A tile (128 x 32) ----
    if (AMODE == 0) {
      const float* ap = (const float*)Aptr + (size_t)(m0 + arow) * Kd + k0 + ac0;
      float4 f0 = ((const float4*)ap)[0];
      float4 f1 = ((const float4*)ap)[1];
      float4 f2 = ((const float4*)ap)[2];
      float4 f3 = ((const float4*)ap)[3];
      short8 s0, s1;
      s0[0] = f2bf(f0.x); s0[1] = f2bf(f0.y); s0[2] = f2bf(f0.z); s0[3] = f2bf(f0.w);
      s0[4] = f2bf(f1.x); s0[5] = f2bf(f1.y); s0[6] = f2bf(f1.z); s0[7] = f2bf(f1.w);
      s1[0] = f2bf(f2.x); s1[1] = f2bf(f2.y); s1[2] = f2bf(f2.z); s1[3] = f2bf(f2.w);
      s1[4] = f2bf(f3.x); s1[5] = f2bf(f3.y); s1[6] = f2bf(f3.z); s1[7] = f2bf(f3.w);
      *(short8*)&As[arow * 40 + ac0]     = s0;
      *(short8*)&As[arow * 40 + ac0 + 8] = s1;
    } else {
      const short* ap = (const short*)Aptr + (size_t)(m0 + arow) * Kd + k0 + ac0;
      *(uint4*)&As[arow * 40 + ac0]     = ((const uint4*)ap)[0];
      *(uint4*)&As[arow * 40 + ac0 + 8] = ((const uint4*)ap)[1];
    }
    // ---- stage B tile (128 n-rows x 32 k) from BT ----
    {
      const short* bp = BT + (size_t)(n0 + arow) * Kd + k0 + ac0;
      *(uint4*)&Bs[arow * 40 + ac0]     = ((const uint4*)bp)[0];
      *(uint4*)&Bs[arow * 40 + ac0 + 8] = ((const uint4*)bp)[1];
    }
    __syncthreads();

    short8 af[4], bfr[4];
#pragma unroll
    for (int mi = 0; mi < 4; ++mi)
      af[mi] = *(const short8*)&As[(wr * 64 + mi * 16 + L) * 40 + g * 8];
#pragma unroll
    for (int ni = 0; ni < 4; ++ni)
      bfr[ni] = *(const short8*)&Bs[(wc * 64 + ni * 16 + L) * 40 + g * 8];
#pragma unroll
    for (int mi = 0; mi < 4; ++mi)
#pragma unroll
      for (int ni = 0; ni < 4; ++ni)
        acc[mi][ni] = MFMA_B16(af[mi], bfr[ni], acc[mi][ni]);
  }

  // ---- epilogue ----
  if (EPI == 0) {
    const int t3 = n0 / kDim;  // 0:Q 1:K 2:V — uniform per block (768 = 6*128)
#pragma unroll
    for (int mi = 0; mi < 4; ++mi) {
#pragma unroll
      for (int ni = 0; ni < 4; ++ni) {
        const int gcol = n0 + wc * 64 + ni * 16 + L;
        const int hd = gcol % kDim;
        const int h = hd >> 6, d = hd & 63;
#pragma unroll
        for (int r = 0; r < 4; ++r) {
          const int grow = m0 + wr * 64 + mi * 16 + 4 * g + r;  // b*1024 + seq
          const int b = grow >> 10, seq = grow & 1023;
          const int bh = b * kHeads + h;
          const short v = f2bf(acc[mi][ni][r]);
          if (t3 == 0)      Qb[((size_t)bh * kSeq + seq) * 64 + d] = v;
          else if (t3 == 1) Kb[((size_t)bh * kSeq + seq) * 64 + d] = v;
          else              VTb[((size_t)bh * 64 + d) * kSeq + seq] = v;
        }
      }
    }
  } else {
#pragma unroll
    for (int ni = 0; ni < 4; ++ni) {
      const int gcol = n0 + wc * 64 + ni * 16 + L;
      const float bv = bias[gcol];
#pragma unroll
      for (int mi = 0; mi < 4; ++mi) {
#pragma unroll
        for (int r = 0; r < 4; ++r) {
          const int grow = m0 + wr * 64 + mi * 16 + 4 * g + r;
          outF[(size_t)grow * kDim + gcol] = acc[mi][ni][r] + bv;
        }
      }
    }
  }
}

// ---------- flash attention -------------------------------------------------
// grid (16 q-tiles, 96 bh), 256 thr. Wave w owns 16 q-rows. KV tiles of 64.
// Q,K row-major [bh][n][64]; V pre-transposed [bh][64][n].
__global__ __launch_bounds__(256) void attn_kernel(const short* __restrict__ Qb,
                                                   const short* __restrict__ Kb,
                                                   const short* __restrict__ VTb,
                                                   short* __restrict__ AO) {
  __shared__ short VTs[64 * 72];      // [d][key], pitch 72 -> balanced banks
  __shared__ short Pls[4][16 * 72];   // per-wave P re-layout buffer

  const int tid  = threadIdx.x;
  const int lane = tid & 63, w = tid >> 6;
  const int L = lane & 15, g = lane >> 4;
  const int qt = blockIdx.x, bh = blockIdx.y;
  const int q0 = qt * 64 + w * 16;

  const short* Qbase = Qb  + (size_t)bh * kSeq * 64;
  const short* Kbase = Kb  + (size_t)bh * kSeq * 64;
  const short* Vbase = VTb + (size_t)bh * 64 * kSeq;

  // Q fragments stay in registers for the whole kernel
  short8 qf[2];
  {
    const short* qp = Qbase + (size_t)(q0 + L) * 64 + g * 8;
    qf[0] = *(const short8*)qp;
    qf[1] = *(const short8*)(qp + 32);
  }

  f32x4 o[4] = {};
  float m_[4], l_[4];
#pragma unroll
  for (int r = 0; r < 4; ++r) { m_[r] = -1e30f; l_[r] = 0.f; }

  for (int t = 0; t < kSeq / 64; ++t) {
    const int kv0 = t * 64;
    __syncthreads();  // prev PV reads of VTs done
    // ---- stage V^T tile: VTs[d][key] (64x64), 16 elems/thread ----
    {
      const int row = tid >> 2, c0 = (tid & 3) * 16;
      const short* src = Vbase + (size_t)row * kSeq + kv0 + c0;
      uint4 v0 = ((const uint4*)src)[0];
      uint4 v1 = ((const uint4*)src)[1];
      *(uint4*)&VTs[row * 72 + c0]     = v0;
      *(uint4*)&VTs[row * 72 + c0 + 8] = v1;
    }
    // ---- S = Q @ K^T (K fragments straight from global, L1/L2-hot) ----
    f32x4 s[4];
#pragma unroll
    for (int nf = 0; nf < 4; ++nf) {
      const short* kp = Kbase + (size_t)(kv0 + nf * 16 + L) * 64 + g * 8;
      short8 kf0 = *(const short8*)kp;
      short8 kf1 = *(const short8*)(kp + 32);
      f32x4 z = {};
      z = MFMA_B16(qf[0], kf0, z);
      s[nf] = MFMA_B16(qf[1], kf1, z);
    }
    // ---- online softmax (row = 4g+reg lives in one 16-lane group) ----
#pragma unroll
    for (int nf = 0; nf < 4; ++nf)
#pragma unroll
      for (int r = 0; r < 4; ++r) s[nf][r] *= kScale;

    float mt[4];
#pragma unroll
    for (int r = 0; r < 4; ++r) {
      float v = fmaxf(fmaxf(s[0][r], s[1][r]), fmaxf(s[2][r], s[3][r]));
#pragma unroll
      for (int off = 1; off < 16; off <<= 1) v = fmaxf(v, __shfl_xor(v, off, 64));
      mt[r] = v;
    }
    float al[4];
#pragma unroll
    for (int r = 0; r < 4; ++r) {
      const float mn = fmaxf(m_[r], mt[r]);
      al[r] = __expf(m_[r] - mn);
      m_[r] = mn;
    }
    float rs[4] = {0.f, 0.f, 0.f, 0.f};
#pragma unroll
    for (int nf = 0; nf < 4; ++nf)
#pragma unroll
      for (int r = 0; r < 4; ++r) {
        const float p = __expf(s[nf][r] - m_[r]);
        s[nf][r] = p;
        rs[r] += p;
      }
#pragma unroll
    for (int r = 0; r < 4; ++r) {
      float v = rs[r];
#pragma unroll
      for (int off = 1; off < 16; off <<= 1) v += __shfl_xor(v, off, 64);
      l_[r] = l_[r] * al[r] + v;
      o[0][r] *= al[r]; o[1][r] *= al[r]; o[2][r] *= al[r]; o[3][r] *= al[r];
    }
    // ---- P: C-layout -> A-layout via wave-private LDS round-trip ----
    short* pw = &Pls[w][0];
#pragma unroll
    for (int nf = 0; nf < 4; ++nf)
#pragma unroll
      for (int r = 0; r < 4; ++r)
        pw[(4 * g + r) * 72 + nf * 16 + L] = f2bf(s[nf][r]);
    asm volatile("s_waitcnt lgkmcnt(0)" ::: "memory");  // wave-local RAW
    short8 pa0 = *(const short8*)&pw[L * 72 + g * 8];
    short8 pa1 = *(const short8*)&pw[L * 72 + 32 + g * 8];

    __syncthreads();  // VTs staged by all waves
    // ---- O += P @ V ----
#pragma unroll
    for (int nf = 0; nf < 4; ++nf) {
      const short* vp = &VTs[(nf * 16 + L) * 72 + g * 8];
      short8 vb0 = *(const short8*)vp;
      short8 vb1 = *(const short8*)(vp + 32);
      o[nf] = MFMA_B16(pa0, vb0, o[nf]);
      o[nf] = MFMA_B16(pa1, vb1, o[nf]);
    }
  }

  // ---- finalize: O /= l, store to AO[b*1024+seq][h*64+d] ----
#pragma unroll
  for (int r = 0; r < 4; ++r) {
    const float inv = 1.0f / l_[r];
    o[0][r] *= inv; o[1][r] *= inv; o[2][r] *= inv; o[3][r] *= inv;
  }
  const int b = bh / kHeads, h = bh % kHeads;
  short* aop = AO + ((size_t)(b * kSeq) + q0) * kDim + h * 64;
#pragma unroll
  for (int nf = 0; nf < 4; ++nf)
#pragma unroll
    for (int r = 0; r < 4; ++r)
      aop[(size_t)(4 * g + r) * kDim + nf * 16 + L] = f2bf(o[nf][r]);
}

// ---------------------------------------------------------------------------
extern "C" void kernel_launch(void* const* d_in, const int* in_sizes, int n_in,
                              void* d_out, int out_size, void* d_ws, size_t ws_size,
                              hipStream_t stream) {
  const float* x     = (const float*)d_in[0];
  const float* w_in  = (const float*)d_in[1];
  const float* w_out = (const float*)d_in[2];
  const float* b_out = (const float*)d_in[3];
  float* out = (float*)d_out;

  // workspace layout (bf16 bits as short), ~52.5 MiB total
  short* WinT  = (short*)d_ws;                          // [2304][768]
  short* WoutT = WinT  + (size_t)2304 * 768;            // [768][768]
  short* Qb    = WoutT + (size_t)768 * 768;             // [96][1024][64]
  short* Kb    = Qb    + (size_t)96 * 1024 * 64;        // [96][1024][64]
  short* VTb   = Kb    + (size_t)96 * 1024 * 64;        // [96][64][1024]
  short* AO    = VTb   + (size_t)96 * 1024 * 64;        // [8192][768]

  transpose_cvt<<<dim3(2304 / 32, 768 / 32), 256, 0, stream>>>(w_in, WinT, 768, 2304);
  transpose_cvt<<<dim3(768 / 32, 768 / 32), 256, 0, stream>>>(w_out, WoutT, 768, 768);

  gemm_tile<0, 0><<<dim3(8192 / 128, 2304 / 128), 256, 0, stream>>>(
      x, WinT, 768, Qb, Kb, VTb, nullptr, nullptr);

  attn_kernel<<<dim3(1024 / 64, 96), 256, 0, stream>>>(Qb, Kb, VTb, AO);

  gemm_tile<1, 1><<<dim3(8192 / 128, 768 / 128), 256, 0, stream>>>(
      AO, WoutT, 768, nullptr, nullptr, nullptr, b_out, out);
}

// Round 2
// 208.270 us; speedup vs baseline: 1.1045x; 1.1045x over previous
//
#include <hip/hip_runtime.h>

// ---------------------------------------------------------------------------
// MultiHeadedAttention: x[8,1024,768] @ w_in[768,2304] -> qkv -> 12-head attn
// (scale = 768^-0.5) -> concat -> @ w_out[768,768] + b_out. f32 in/out,
// bf16 MFMA internally.
// ---------------------------------------------------------------------------

using short8 = __attribute__((ext_vector_type(8))) short;  // 8 bf16 (4 VGPR)
using f32x4  = __attribute__((ext_vector_type(4))) float;  // MFMA acc

#define MFMA_B16(a, b, c) __builtin_amdgcn_mfma_f32_16x16x32_bf16((a), (b), (c), 0, 0, 0)

constexpr int   kDim   = 768;
constexpr int   kHeads = 12;
constexpr int   kSeq   = 1024;
constexpr float kScale = 0.03608439182435161f;  // 768^-0.5 (full dim, per ref)

__device__ __forceinline__ short f2bf(float f) {  // RNE f32 -> bf16 bits
  unsigned u = __float_as_uint(f);
  u += 0x7FFFu + ((u >> 16) & 1u);
  return (short)(u >> 16);
}

// ---------- transpose + convert: out[c][r] = bf16(in[r][c]) ----------------
__global__ __launch_bounds__(256) void transpose_cvt(const float* __restrict__ in,
                                                     short* __restrict__ out,
                                                     int R, int C) {
  __shared__ float tile[32][33];
  const int c0 = blockIdx.x * 32, r0 = blockIdx.y * 32;
  const int tx = threadIdx.x & 31, ty = threadIdx.x >> 5;
#pragma unroll
  for (int i = 0; i < 32; i += 8)
    tile[ty + i][tx] = in[(size_t)(r0 + ty + i) * C + c0 + tx];
  __syncthreads();
#pragma unroll
  for (int i = 0; i < 32; i += 8)
    out[(size_t)(c0 + ty + i) * R + r0 + tx] = f2bf(tile[tx][ty + i]);
}

// ---------- 128x128 MFMA GEMM, BK=32, 4 waves ------------------------------
template <int AMODE, int EPI>
__global__ __launch_bounds__(256) void gemm_tile(const void* __restrict__ Aptr,
                                                 const short* __restrict__ BT,
                                                 int Kd,
                                                 short* __restrict__ Qb,
                                                 short* __restrict__ Kb,
                                                 short* __restrict__ VTb,
                                                 const float* __restrict__ bias,
                                                 float* __restrict__ outF) {
  __shared__ short As[128 * 40];
  __shared__ short Bs[128 * 40];

  const int tid  = threadIdx.x;
  const int lane = tid & 63, w = tid >> 6;
  const int L = lane & 15, g = lane >> 4;
  const int wr = w >> 1, wc = w & 1;
  const int m0 = blockIdx.x * 128, n0 = blockIdx.y * 128;

  const int arow = tid >> 1;
  const int ac0  = (tid & 1) * 16;

  f32x4 acc[4][4] = {};

  for (int k0 = 0; k0 < Kd; k0 += 32) {
    __syncthreads();
    if (AMODE == 0) {
      const float* ap = (const float*)Aptr + (size_t)(m0 + arow) * Kd + k0 + ac0;
      float4 f0 = ((const float4*)ap)[0];
      float4 f1 = ((const float4*)ap)[1];
      float4 f2 = ((const float4*)ap)[2];
      float4 f3 = ((const float4*)ap)[3];
      short8 s0, s1;
      s0[0] = f2bf(f0.x); s0[1] = f2bf(f0.y); s0[2] = f2bf(f0.z); s0[3] = f2bf(f0.w);
      s0[4] = f2bf(f1.x); s0[5] = f2bf(f1.y); s0[6] = f2bf(f1.z); s0[7] = f2bf(f1.w);
      s1[0] = f2bf(f2.x); s1[1] = f2bf(f2.y); s1[2] = f2bf(f2.z); s1[3] = f2bf(f2.w);
      s1[4] = f2bf(f3.x); s1[5] = f2bf(f3.y); s1[6] = f2bf(f3.z); s1[7] = f2bf(f3.w);
      *(short8*)&As[arow * 40 + ac0]     = s0;
      *(short8*)&As[arow * 40 + ac0 + 8] = s1;
    } else {
      const short* ap = (const short*)Aptr + (size_t)(m0 + arow) * Kd + k0 + ac0;
      *(uint4*)&As[arow * 40 + ac0]     = ((const uint4*)ap)[0];
      *(uint4*)&As[arow * 40 + ac0 + 8] = ((const uint4*)ap)[1];
    }
    {
      const short* bp = BT + (size_t)(n0 + arow) * Kd + k0 + ac0;
      *(uint4*)&Bs[arow * 40 + ac0]     = ((const uint4*)bp)[0];
      *(uint4*)&Bs[arow * 40 + ac0 + 8] = ((const uint4*)bp)[1];
    }
    __syncthreads();

    short8 af[4], bfr[4];
#pragma unroll
    for (int mi = 0; mi < 4; ++mi)
      af[mi] = *(const short8*)&As[(wr * 64 + mi * 16 + L) * 40 + g * 8];
#pragma unroll
    for (int ni = 0; ni < 4; ++ni)
      bfr[ni] = *(const short8*)&Bs[(wc * 64 + ni * 16 + L) * 40 + g * 8];
#pragma unroll
    for (int mi = 0; mi < 4; ++mi)
#pragma unroll
      for (int ni = 0; ni < 4; ++ni)
        acc[mi][ni] = MFMA_B16(af[mi], bfr[ni], acc[mi][ni]);
  }

  if (EPI == 0) {
    const int t3 = n0 / kDim;
#pragma unroll
    for (int mi = 0; mi < 4; ++mi) {
#pragma unroll
      for (int ni = 0; ni < 4; ++ni) {
        const int gcol = n0 + wc * 64 + ni * 16 + L;
        const int hd = gcol % kDim;
        const int h = hd >> 6, d = hd & 63;
#pragma unroll
        for (int r = 0; r < 4; ++r) {
          const int grow = m0 + wr * 64 + mi * 16 + 4 * g + r;
          const int b = grow >> 10, seq = grow & 1023;
          const int bh = b * kHeads + h;
          const short v = f2bf(acc[mi][ni][r]);
          if (t3 == 0)      Qb[((size_t)bh * kSeq + seq) * 64 + d] = v;
          else if (t3 == 1) Kb[((size_t)bh * kSeq + seq) * 64 + d] = v;
          else              VTb[((size_t)bh * 64 + d) * kSeq + seq] = v;
        }
      }
    }
  } else {
#pragma unroll
    for (int ni = 0; ni < 4; ++ni) {
      const int gcol = n0 + wc * 64 + ni * 16 + L;
      const float bv = bias[gcol];
#pragma unroll
      for (int mi = 0; mi < 4; ++mi) {
#pragma unroll
        for (int r = 0; r < 4; ++r) {
          const int grow = m0 + wr * 64 + mi * 16 + 4 * g + r;
          outF[(size_t)grow * kDim + gcol] = acc[mi][ni][r] + bv;
        }
      }
    }
  }
}

// ---------- flash attention v2 ---------------------------------------------
// 1D grid of 768 blocks: id = qc*96 + bh  -> id%8 == bh%8, so all q-chunks of
// a bh land on the same XCD (round-robin dispatch) and K/V stay L2-resident.
// Block: 4 waves x 32 q-rows = 128 q-rows. KV tiles of 64 keys, K AND V
// staged cooperatively in LDS (pitch 72), double-buffered, reg-staged with
// async-split (issue loads at loop top, ds_write after PV), ONE barrier/tile.
__global__ __launch_bounds__(256) void attn_kernel(const short* __restrict__ Qb,
                                                   const short* __restrict__ Kb,
                                                   const short* __restrict__ VTb,
                                                   short* __restrict__ AO) {
  __shared__ short Ks[2][64 * 72];   // [key][d]
  __shared__ short VTs[2][64 * 72];  // [d][key]
  __shared__ short Pls[4][16 * 72];  // per-wave P re-layout buffer

  const int tid  = threadIdx.x;
  const int lane = tid & 63, w = tid >> 6;
  const int L = lane & 15, g = lane >> 4;
  const int id = blockIdx.x;
  const int bh = id % 96, qc = id / 96;
  const int q0 = qc * 128 + w * 32;

  const short* Qbase = Qb  + (size_t)bh * kSeq * 64;
  const short* Kbase = Kb  + (size_t)bh * kSeq * 64;
  const short* Vbase = VTb + (size_t)bh * 64 * kSeq;

  // Q fragments (2 q-halves x 2 k-chunks) stay in registers
  short8 qf[2][2];
#pragma unroll
  for (int qh = 0; qh < 2; ++qh) {
    const short* qp = Qbase + (size_t)(q0 + qh * 16 + L) * 64 + g * 8;
    qf[qh][0] = *(const short8*)qp;
    qf[qh][1] = *(const short8*)(qp + 32);
  }

  f32x4 o[2][4] = {};
  float m_[2][4], l_[2][4];
#pragma unroll
  for (int qh = 0; qh < 2; ++qh)
#pragma unroll
    for (int r = 0; r < 4; ++r) { m_[qh][r] = -1e30f; l_[qh][r] = 0.f; }

  const int srow = tid >> 2, sc0 = (tid & 3) * 16;  // staging: 16 elems/thread

  // ---- prologue: stage tile 0 ----
  {
    const short* ksrc = Kbase + (size_t)srow * 64 + sc0;
    const short* vsrc = Vbase + (size_t)srow * kSeq + sc0;
    uint4 k0 = ((const uint4*)ksrc)[0], k1 = ((const uint4*)ksrc)[1];
    uint4 v0 = ((const uint4*)vsrc)[0], v1 = ((const uint4*)vsrc)[1];
    *(uint4*)&Ks[0][srow * 72 + sc0]      = k0;
    *(uint4*)&Ks[0][srow * 72 + sc0 + 8]  = k1;
    *(uint4*)&VTs[0][srow * 72 + sc0]     = v0;
    *(uint4*)&VTs[0][srow * 72 + sc0 + 8] = v1;
  }
  __syncthreads();

  for (int t = 0; t < kSeq / 64; ++t) {
    const int cur = t & 1;
    const bool pf = (t + 1 < kSeq / 64);

    // ---- issue next-tile loads early (T14 async split) ----
    uint4 kr0, kr1, vr0, vr1;
    if (pf) {
      const int kv1 = (t + 1) * 64;
      const short* ksrc = Kbase + (size_t)(kv1 + srow) * 64 + sc0;
      const short* vsrc = Vbase + (size_t)srow * kSeq + kv1 + sc0;
      kr0 = ((const uint4*)ksrc)[0]; kr1 = ((const uint4*)ksrc)[1];
      vr0 = ((const uint4*)vsrc)[0]; vr1 = ((const uint4*)vsrc)[1];
    }

    short8 pa[2][2];
#pragma unroll
    for (int qh = 0; qh < 2; ++qh) {
      // ---- S = Q @ K^T (K from LDS) ----
      f32x4 s[4];
#pragma unroll
      for (int nf = 0; nf < 4; ++nf) {
        const short* kp = &Ks[cur][(nf * 16 + L) * 72 + g * 8];
        short8 kf0 = *(const short8*)kp;
        short8 kf1 = *(const short8*)(kp + 32);
        f32x4 z = {};
        z = MFMA_B16(qf[qh][0], kf0, z);
        s[nf] = MFMA_B16(qf[qh][1], kf1, z);
      }
      // ---- online softmax ----
#pragma unroll
      for (int nf = 0; nf < 4; ++nf)
#pragma unroll
        for (int r = 0; r < 4; ++r) s[nf][r] *= kScale;

#pragma unroll
      for (int r = 0; r < 4; ++r) {
        float v = fmaxf(fmaxf(s[0][r], s[1][r]), fmaxf(s[2][r], s[3][r]));
#pragma unroll
        for (int off = 1; off < 16; off <<= 1) v = fmaxf(v, __shfl_xor(v, off, 64));
        const float mn = fmaxf(m_[qh][r], v);
        const float al = __expf(m_[qh][r] - mn);
        m_[qh][r] = mn;
        l_[qh][r] *= al;
        o[qh][0][r] *= al; o[qh][1][r] *= al; o[qh][2][r] *= al; o[qh][3][r] *= al;
      }
      float rs[4] = {0.f, 0.f, 0.f, 0.f};
#pragma unroll
      for (int nf = 0; nf < 4; ++nf)
#pragma unroll
        for (int r = 0; r < 4; ++r) {
          const float p = __expf(s[nf][r] - m_[qh][r]);
          s[nf][r] = p;
          rs[r] += p;
        }
#pragma unroll
      for (int r = 0; r < 4; ++r) {
        float v = rs[r];
#pragma unroll
        for (int off = 1; off < 16; off <<= 1) v += __shfl_xor(v, off, 64);
        l_[qh][r] += v;
      }
      // ---- P: C-layout -> A-layout via wave-private LDS round-trip ----
      short* pw = &Pls[w][0];
#pragma unroll
      for (int nf = 0; nf < 4; ++nf)
#pragma unroll
        for (int r = 0; r < 4; ++r)
          pw[(4 * g + r) * 72 + nf * 16 + L] = f2bf(s[nf][r]);
      asm volatile("s_waitcnt lgkmcnt(0)" ::: "memory");
      pa[qh][0] = *(const short8*)&pw[L * 72 + g * 8];
      pa[qh][1] = *(const short8*)&pw[L * 72 + 32 + g * 8];
      asm volatile("s_waitcnt lgkmcnt(0)" ::: "memory");  // drain before qh=1 reuse
    }

    // ---- O += P @ V (V from LDS, fragments shared across q-halves) ----
#pragma unroll
    for (int nf = 0; nf < 4; ++nf) {
      const short* vp = &VTs[cur][(nf * 16 + L) * 72 + g * 8];
      short8 vb0 = *(const short8*)vp;
      short8 vb1 = *(const short8*)(vp + 32);
#pragma unroll
      for (int qh = 0; qh < 2; ++qh) {
        o[qh][nf] = MFMA_B16(pa[qh][0], vb0, o[qh][nf]);
        o[qh][nf] = MFMA_B16(pa[qh][1], vb1, o[qh][nf]);
      }
    }

    // ---- write next tile into the other buffer, one barrier per tile ----
    if (pf) {
      *(uint4*)&Ks[cur ^ 1][srow * 72 + sc0]      = kr0;
      *(uint4*)&Ks[cur ^ 1][srow * 72 + sc0 + 8]  = kr1;
      *(uint4*)&VTs[cur ^ 1][srow * 72 + sc0]     = vr0;
      *(uint4*)&VTs[cur ^ 1][srow * 72 + sc0 + 8] = vr1;
    }
    __syncthreads();
  }

  // ---- finalize: O /= l, store ----
  const int b = bh / kHeads, h = bh % kHeads;
#pragma unroll
  for (int qh = 0; qh < 2; ++qh) {
    short* aop = AO + ((size_t)(b * kSeq) + q0 + qh * 16) * kDim + h * 64;
#pragma unroll
    for (int r = 0; r < 4; ++r) {
      const float inv = 1.0f / l_[qh][r];
#pragma unroll
      for (int nf = 0; nf < 4; ++nf)
        aop[(size_t)(4 * g + r) * kDim + nf * 16 + L] = f2bf(o[qh][nf][r] * inv);
    }
  }
}

// ---------------------------------------------------------------------------
extern "C" void kernel_launch(void* const* d_in, const int* in_sizes, int n_in,
                              void* d_out, int out_size, void* d_ws, size_t ws_size,
                              hipStream_t stream) {
  const float* x     = (const float*)d_in[0];
  const float* w_in  = (const float*)d_in[1];
  const float* w_out = (const float*)d_in[2];
  const float* b_out = (const float*)d_in[3];
  float* out = (float*)d_out;

  short* WinT  = (short*)d_ws;                          // [2304][768]
  short* WoutT = WinT  + (size_t)2304 * 768;            // [768][768]
  short* Qb    = WoutT + (size_t)768 * 768;             // [96][1024][64]
  short* Kb    = Qb    + (size_t)96 * 1024 * 64;        // [96][1024][64]
  short* VTb   = Kb    + (size_t)96 * 1024 * 64;        // [96][64][1024]
  short* AO    = VTb   + (size_t)96 * 1024 * 64;        // [8192][768]

  transpose_cvt<<<dim3(2304 / 32, 768 / 32), 256, 0, stream>>>(w_in, WinT, 768, 2304);
  transpose_cvt<<<dim3(768 / 32, 768 / 32), 256, 0, stream>>>(w_out, WoutT, 768, 768);

  gemm_tile<0, 0><<<dim3(8192 / 128, 2304 / 128), 256, 0, stream>>>(
      x, WinT, 768, Qb, Kb, VTb, nullptr, nullptr);

  attn_kernel<<<dim3(768), 256, 0, stream>>>(Qb, Kb, VTb, AO);

  gemm_tile<1, 1><<<dim3(8192 / 128, 768 / 128), 256, 0, stream>>>(
      AO, WoutT, 768, nullptr, nullptr, nullptr, b_out, out);
}

// Round 3
// 165.872 us; speedup vs baseline: 1.3869x; 1.2556x over previous
//
#include <hip/hip_runtime.h>

// ---------------------------------------------------------------------------
// MultiHeadedAttention: x[8,1024,768] @ w_in[768,2304] -> qkv -> 12-head attn
// (scale = 768^-0.5) -> concat -> @ w_out[768,768] + b_out. f32 in/out,
// bf16 MFMA internally. Attn uses swapped QK^T (mfma(K,Q)) so softmax rows
// are lane-local; exp2 domain with scale*log2e folded into Q at GEMM1 epi.
// ---------------------------------------------------------------------------

using short8 = __attribute__((ext_vector_type(8))) short;  // 8 bf16 (4 VGPR)
using f32x4  = __attribute__((ext_vector_type(4))) float;  // MFMA acc

#define MFMA_B16(a, b, c) __builtin_amdgcn_mfma_f32_16x16x32_bf16((a), (b), (c), 0, 0, 0)

typedef const __attribute__((address_space(1))) void* gvoid_p;
typedef __attribute__((address_space(3))) void* lvoid_p;

constexpr int   kDim   = 768;
constexpr int   kHeads = 12;
constexpr int   kSeq   = 1024;
constexpr float kScale = 0.03608439182435161f;             // 768^-0.5 (full dim)
constexpr float kQSc   = kScale * 1.4426950408889634f;     // fold log2(e) into Q

__device__ __forceinline__ short f2bf(float f) {  // RNE f32 -> bf16 bits
  unsigned u = __float_as_uint(f);
  u += 0x7FFFu + ((u >> 16) & 1u);
  return (short)(u >> 16);
}
__device__ __forceinline__ unsigned pk2(float lo, float hi) {
  return (unsigned)(unsigned short)f2bf(lo) | ((unsigned)(unsigned short)f2bf(hi) << 16);
}

// ---------- x: f32 -> bf16 cast (exact-size grid) ---------------------------
__global__ __launch_bounds__(256) void cvt_f32_bf16(const float* __restrict__ in,
                                                    short* __restrict__ out) {
  const int i = blockIdx.x * 256 + threadIdx.x;  // one short8 per thread
  float4 a = ((const float4*)in)[i * 2];
  float4 b = ((const float4*)in)[i * 2 + 1];
  short8 s;
  s[0] = f2bf(a.x); s[1] = f2bf(a.y); s[2] = f2bf(a.z); s[3] = f2bf(a.w);
  s[4] = f2bf(b.x); s[5] = f2bf(b.y); s[6] = f2bf(b.z); s[7] = f2bf(b.w);
  ((short8*)out)[i] = s;
}

// ---------- transpose + convert: out[c][r] = bf16(in[r][c]) ----------------
__global__ __launch_bounds__(256) void transpose_cvt(const float* __restrict__ in,
                                                     short* __restrict__ out,
                                                     int R, int C) {
  __shared__ float tile[32][33];
  const int c0 = blockIdx.x * 32, r0 = blockIdx.y * 32;
  const int tx = threadIdx.x & 31, ty = threadIdx.x >> 5;
#pragma unroll
  for (int i = 0; i < 32; i += 8)
    tile[ty + i][tx] = in[(size_t)(r0 + ty + i) * C + c0 + tx];
  __syncthreads();
#pragma unroll
  for (int i = 0; i < 32; i += 8)
    out[(size_t)(c0 + ty + i) * R + r0 + tx] = f2bf(tile[tx][ty + i]);
}

// ---------- 128x128 MFMA GEMM, BK=32, 4 waves, global_load_lds staging -----
// A[M][K] bf16; BT[n][k] bf16. Linear LDS [128][32] (m97 recipe).
// EPI 0: scatter qkv to Q (pre-scaled by kQSc), K, V^T.  EPI 1: +bias, f32.
template <int EPI>
__global__ __launch_bounds__(256) void gemm_tile(const short* __restrict__ A,
                                                 const short* __restrict__ BT,
                                                 int Kd,
                                                 short* __restrict__ Qb,
                                                 short* __restrict__ Kb,
                                                 short* __restrict__ VTb,
                                                 const float* __restrict__ bias,
                                                 float* __restrict__ outF) {
  __shared__ short As[128 * 32];
  __shared__ short Bs[128 * 32];

  const int tid  = threadIdx.x;
  const int lane = tid & 63, w = tid >> 6;
  const int L = lane & 15, g = lane >> 4;
  const int wr = w >> 1, wc = w & 1;
  const int m0 = blockIdx.x * 128, n0 = blockIdx.y * 128;

  const int r4 = lane >> 2;        // row within 16-row chunk
  const int c8 = (lane & 3) * 8;   // k-col (shorts)

  f32x4 acc[4][4] = {};

  for (int k0 = 0; k0 < Kd; k0 += 32) {
    __syncthreads();  // previous compute done before overwrite
#pragma unroll
    for (int c = 0; c < 2; ++c) {
      const short* ag = A  + (size_t)(m0 + w * 32 + c * 16 + r4) * Kd + k0 + c8;
      const short* bg = BT + (size_t)(n0 + w * 32 + c * 16 + r4) * Kd + k0 + c8;
      __builtin_amdgcn_global_load_lds((gvoid_p)ag, (lvoid_p)&As[(w * 2 + c) * 512], 16, 0, 0);
      __builtin_amdgcn_global_load_lds((gvoid_p)bg, (lvoid_p)&Bs[(w * 2 + c) * 512], 16, 0, 0);
    }
    __syncthreads();  // drains vmcnt -> LDS tiles ready

    short8 af[4], bfr[4];
#pragma unroll
    for (int mi = 0; mi < 4; ++mi)
      af[mi] = *(const short8*)&As[(wr * 64 + mi * 16 + L) * 32 + g * 8];
#pragma unroll
    for (int ni = 0; ni < 4; ++ni)
      bfr[ni] = *(const short8*)&Bs[(wc * 64 + ni * 16 + L) * 32 + g * 8];
#pragma unroll
    for (int mi = 0; mi < 4; ++mi)
#pragma unroll
      for (int ni = 0; ni < 4; ++ni)
        acc[mi][ni] = MFMA_B16(af[mi], bfr[ni], acc[mi][ni]);
  }

  if (EPI == 0) {
    const int t3 = n0 / kDim;  // 0:Q 1:K 2:V (uniform per block; 768 = 6*128)
#pragma unroll
    for (int mi = 0; mi < 4; ++mi) {
#pragma unroll
      for (int ni = 0; ni < 4; ++ni) {
        const int gcol = n0 + wc * 64 + ni * 16 + L;
        const int hd = gcol % kDim;
        const int h = hd >> 6, d = hd & 63;
#pragma unroll
        for (int r = 0; r < 4; ++r) {
          const int grow = m0 + wr * 64 + mi * 16 + 4 * g + r;  // b*1024 + seq
          const int b = grow >> 10, seq = grow & 1023;
          const int bh = b * kHeads + h;
          if (t3 == 0)      Qb[((size_t)bh * kSeq + seq) * 64 + d] = f2bf(acc[mi][ni][r] * kQSc);
          else if (t3 == 1) Kb[((size_t)bh * kSeq + seq) * 64 + d] = f2bf(acc[mi][ni][r]);
          else              VTb[((size_t)bh * 64 + d) * kSeq + seq] = f2bf(acc[mi][ni][r]);
        }
      }
    }
  } else {
#pragma unroll
    for (int ni = 0; ni < 4; ++ni) {
      const int gcol = n0 + wc * 64 + ni * 16 + L;
      const float bv = bias[gcol];
#pragma unroll
      for (int mi = 0; mi < 4; ++mi) {
#pragma unroll
        for (int r = 0; r < 4; ++r) {
          const int grow = m0 + wr * 64 + mi * 16 + 4 * g + r;
          outF[(size_t)grow * kDim + gcol] = acc[mi][ni][r] + bv;
        }
      }
    }
  }
}

// ---------- flash attention v3 (swapped QK^T, in-register softmax) ---------
// 1D grid 768: id%8 == bh%8 -> per-bh K/V stays XCD-L2-resident.
// Wave w: 32 q-rows. S^T = mfma(K, Q): lane holds S[16 keys][query L].
// Row max/sum: in-reg tree + shfl_xor(16,32). exp2 domain (Q pre-scaled).
// Defer-max (thr=8 log2-units) skips O-rescale on most tiles.
// P relayout: 4 ds_write_b64 + 2 ds_read_b128 per q-half (2-way conflicts).
__global__ __launch_bounds__(256) void attn_kernel(const short* __restrict__ Qb,
                                                   const short* __restrict__ Kb,
                                                   const short* __restrict__ VTb,
                                                   short* __restrict__ AO) {
  __shared__ short Ks[2][64 * 72];   // [key][d]
  __shared__ short VTs[2][64 * 72];  // [d][key]
  __shared__ short Pls[4][16 * 72];  // per-wave P[query][key] relayout buffer

  const int tid  = threadIdx.x;
  const int lane = tid & 63, w = tid >> 6;
  const int L = lane & 15, g = lane >> 4;
  const int id = blockIdx.x;
  const int bh = id % 96, qc = id / 96;
  const int q0 = qc * 128 + w * 32;

  const short* Qbase = Qb  + (size_t)bh * kSeq * 64;
  const short* Kbase = Kb  + (size_t)bh * kSeq * 64;
  const short* Vbase = VTb + (size_t)bh * 64 * kSeq;

  short8 qf[2][2];  // Q (pre-scaled by kQSc) as B-operand, resident in regs
#pragma unroll
  for (int qh = 0; qh < 2; ++qh) {
    const short* qp = Qbase + (size_t)(q0 + qh * 16 + L) * 64 + g * 8;
    qf[qh][0] = *(const short8*)qp;
    qf[qh][1] = *(const short8*)(qp + 32);
  }

  f32x4 o[2][4] = {};
  float m_[2] = {-1e30f, -1e30f};
  float l_[2] = {0.f, 0.f};

  const int srow = tid >> 2, sc0 = (tid & 3) * 16;  // staging: 16 elems/thread

  {  // prologue: stage tile 0
    const short* ksrc = Kbase + (size_t)srow * 64 + sc0;
    const short* vsrc = Vbase + (size_t)srow * kSeq + sc0;
    uint4 k0 = ((const uint4*)ksrc)[0], k1 = ((const uint4*)ksrc)[1];
    uint4 v0 = ((const uint4*)vsrc)[0], v1 = ((const uint4*)vsrc)[1];
    *(uint4*)&Ks[0][srow * 72 + sc0]      = k0;
    *(uint4*)&Ks[0][srow * 72 + sc0 + 8]  = k1;
    *(uint4*)&VTs[0][srow * 72 + sc0]     = v0;
    *(uint4*)&VTs[0][srow * 72 + sc0 + 8] = v1;
  }
  __syncthreads();

  for (int t = 0; t < kSeq / 64; ++t) {
    const int cur = t & 1;
    const bool pf = (t + 1 < kSeq / 64);

    // ---- issue next-tile loads early (T14 async split) ----
    uint4 kr0, kr1, vr0, vr1;
    if (pf) {
      const int kv1 = (t + 1) * 64;
      const short* ksrc = Kbase + (size_t)(kv1 + srow) * 64 + sc0;
      const short* vsrc = Vbase + (size_t)srow * kSeq + kv1 + sc0;
      kr0 = ((const uint4*)ksrc)[0]; kr1 = ((const uint4*)ksrc)[1];
      vr0 = ((const uint4*)vsrc)[0]; vr1 = ((const uint4*)vsrc)[1];
    }

    // ---- K fragments (A-operand), shared across both q-halves ----
    short8 kf[4][2];
#pragma unroll
    for (int nf = 0; nf < 4; ++nf) {
      const short* kp = &Ks[cur][(nf * 16 + L) * 72 + g * 8];
      kf[nf][0] = *(const short8*)kp;
      kf[nf][1] = *(const short8*)(kp + 32);
    }

    short8 pa[2][2];
#pragma unroll
    for (int qh = 0; qh < 2; ++qh) {
      // ---- S^T = K @ Q^T: lane holds S[key=nf*16+4g+r][query=L] ----
      f32x4 s[4];
#pragma unroll
      for (int nf = 0; nf < 4; ++nf) {
        f32x4 z = {};
        z = MFMA_B16(kf[nf][0], qf[qh][0], z);
        s[nf] = MFMA_B16(kf[nf][1], qf[qh][1], z);
      }
      // ---- row max: 16 in-reg + cross-g reduce (2 shfl) ----
      float x0 = fmaxf(fmaxf(s[0][0], s[0][1]), fmaxf(s[0][2], s[0][3]));
      float x1 = fmaxf(fmaxf(s[1][0], s[1][1]), fmaxf(s[1][2], s[1][3]));
      float x2 = fmaxf(fmaxf(s[2][0], s[2][1]), fmaxf(s[2][2], s[2][3]));
      float x3 = fmaxf(fmaxf(s[3][0], s[3][1]), fmaxf(s[3][2], s[3][3]));
      float mt = fmaxf(fmaxf(x0, x1), fmaxf(x2, x3));
      mt = fmaxf(mt, __shfl_xor(mt, 16, 64));
      mt = fmaxf(mt, __shfl_xor(mt, 32, 64));

      const bool grow = __any(mt > m_[qh] + 8.0f);  // defer-max (T13)
      const float mnew = grow ? fmaxf(m_[qh], mt) : m_[qh];

      // ---- p = exp2(s - m), pack to bf16, write P[query][key] to LDS ----
      float rsum = 0.f;
      short* pw = &Pls[w][0];
#pragma unroll
      for (int nf = 0; nf < 4; ++nf) {
        const float p0 = exp2f(s[nf][0] - mnew);
        const float p1 = exp2f(s[nf][1] - mnew);
        const float p2 = exp2f(s[nf][2] - mnew);
        const float p3 = exp2f(s[nf][3] - mnew);
        rsum += (p0 + p1) + (p2 + p3);
        uint2 d2; d2.x = pk2(p0, p1); d2.y = pk2(p2, p3);
        *(uint2*)&pw[L * 72 + nf * 16 + 4 * g] = d2;
      }
      rsum += __shfl_xor(rsum, 16, 64);
      rsum += __shfl_xor(rsum, 32, 64);

      if (grow) {
        const float al = exp2f(m_[qh] - mnew);
        m_[qh] = mnew;
        l_[qh] = l_[qh] * al + rsum;
        float alr[4];
#pragma unroll
        for (int r = 0; r < 4; ++r) alr[r] = __shfl(al, 4 * g + r, 64);
#pragma unroll
        for (int nf = 0; nf < 4; ++nf)
#pragma unroll
          for (int r = 0; r < 4; ++r) o[qh][nf][r] *= alr[r];
      } else {
        l_[qh] += rsum;
      }

      // ---- read P back as A-fragment ----
      asm volatile("s_waitcnt lgkmcnt(0)" ::: "memory");
      pa[qh][0] = *(const short8*)&pw[L * 72 + g * 8];
      pa[qh][1] = *(const short8*)&pw[L * 72 + 32 + g * 8];
      asm volatile("s_waitcnt lgkmcnt(0)" ::: "memory");  // reads done before qh=1 reuse
    }

    // ---- O += P @ V (V fragments shared across q-halves) ----
#pragma unroll
    for (int nf = 0; nf < 4; ++nf) {
      const short* vp = &VTs[cur][(nf * 16 + L) * 72 + g * 8];
      short8 vb0 = *(const short8*)vp;
      short8 vb1 = *(const short8*)(vp + 32);
#pragma unroll
      for (int qh = 0; qh < 2; ++qh) {
        o[qh][nf] = MFMA_B16(pa[qh][0], vb0, o[qh][nf]);
        o[qh][nf] = MFMA_B16(pa[qh][1], vb1, o[qh][nf]);
      }
    }

    // ---- write prefetched tile into other buffer; one barrier per tile ----
    if (pf) {
      *(uint4*)&Ks[cur ^ 1][srow * 72 + sc0]      = kr0;
      *(uint4*)&Ks[cur ^ 1][srow * 72 + sc0 + 8]  = kr1;
      *(uint4*)&VTs[cur ^ 1][srow * 72 + sc0]     = vr0;
      *(uint4*)&VTs[cur ^ 1][srow * 72 + sc0 + 8] = vr1;
    }
    __syncthreads();
  }

  // ---- finalize: O /= l (l gathered per output-row), store ----
  const int b = bh / kHeads, h = bh % kHeads;
#pragma unroll
  for (int qh = 0; qh < 2; ++qh) {
    float lq[4];
#pragma unroll
    for (int r = 0; r < 4; ++r) lq[r] = __shfl(l_[qh], 4 * g + r, 64);
    short* aop = AO + ((size_t)(b * kSeq) + q0 + qh * 16) * kDim + h * 64;
#pragma unroll
    for (int r = 0; r < 4; ++r) {
      const float inv = 1.0f / lq[r];
#pragma unroll
      for (int nf = 0; nf < 4; ++nf)
        aop[(size_t)(4 * g + r) * kDim + nf * 16 + L] = f2bf(o[qh][nf][r] * inv);
    }
  }
}

// ---------------------------------------------------------------------------
extern "C" void kernel_launch(void* const* d_in, const int* in_sizes, int n_in,
                              void* d_out, int out_size, void* d_ws, size_t ws_size,
                              hipStream_t stream) {
  const float* x     = (const float*)d_in[0];
  const float* w_in  = (const float*)d_in[1];
  const float* w_out = (const float*)d_in[2];
  const float* b_out = (const float*)d_in[3];
  float* out = (float*)d_out;

  // workspace (bf16 as short). xbf aliases AO: xbf dead before attn writes AO.
  short* WinT  = (short*)d_ws;                          // [2304][768]
  short* WoutT = WinT  + (size_t)2304 * 768;            // [768][768]
  short* Qb    = WoutT + (size_t)768 * 768;             // [96][1024][64]
  short* Kb    = Qb    + (size_t)96 * 1024 * 64;        // [96][1024][64]
  short* VTb   = Kb    + (size_t)96 * 1024 * 64;        // [96][64][1024]
  short* AO    = VTb   + (size_t)96 * 1024 * 64;        // [8192][768]
  short* xbf   = AO;                                    // alias (see above)

  cvt_f32_bf16<<<dim3(8192 * 768 / (256 * 8)), 256, 0, stream>>>(x, xbf);
  transpose_cvt<<<dim3(2304 / 32, 768 / 32), 256, 0, stream>>>(w_in, WinT, 768, 2304);
  transpose_cvt<<<dim3(768 / 32, 768 / 32), 256, 0, stream>>>(w_out, WoutT, 768, 768);

  gemm_tile<0><<<dim3(8192 / 128, 2304 / 128), 256, 0, stream>>>(
      xbf, WinT, 768, Qb, Kb, VTb, nullptr, nullptr);

  attn_kernel<<<dim3(768), 256, 0, stream>>>(Qb, Kb, VTb, AO);

  gemm_tile<1><<<dim3(8192 / 128, 768 / 128), 256, 0, stream>>>(
      AO, WoutT, 768, nullptr, nullptr, nullptr, b_out, out);
}

// Round 4
// 138.094 us; speedup vs baseline: 1.6658x; 1.2011x over previous
//
#include <hip/hip_runtime.h>

// ---------------------------------------------------------------------------
// MultiHeadedAttention: x[8,1024,768] @ w_in[768,2304] -> qkv -> 12-head attn
// (scale = 768^-0.5) -> concat -> @ w_out[768,768] + b_out. f32 in/out,
// bf16 MFMA internally. Attn: swapped QK^T + k-axis permutation so P never
// leaves registers (cvt_pk packing); V B-fragments absorb the permutation.
// ---------------------------------------------------------------------------

using short8 = __attribute__((ext_vector_type(8))) short;  // 8 bf16 (4 VGPR)
using s16x4  = __attribute__((ext_vector_type(4))) short;  // 4 bf16 (b64)
using f32x4  = __attribute__((ext_vector_type(4))) float;  // MFMA acc

#define MFMA_B16(a, b, c) __builtin_amdgcn_mfma_f32_16x16x32_bf16((a), (b), (c), 0, 0, 0)

typedef const __attribute__((address_space(1))) void* gvoid_p;
typedef __attribute__((address_space(3))) void* lvoid_p;

constexpr int   kDim   = 768;
constexpr int   kHeads = 12;
constexpr int   kSeq   = 1024;
constexpr float kScale = 0.03608439182435161f;             // 768^-0.5 (full dim)
constexpr float kQSc   = kScale * 1.4426950408889634f;     // fold log2(e) into Q

__device__ __forceinline__ short f2bf(float f) {  // RNE f32 -> bf16 bits
  unsigned u = __float_as_uint(f);
  u += 0x7FFFu + ((u >> 16) & 1u);
  return (short)(u >> 16);
}
__device__ __forceinline__ unsigned cvt_pk_bf16(float lo, float hi) {
  unsigned r;
  asm("v_cvt_pk_bf16_f32 %0, %1, %2" : "=v"(r) : "v"(lo), "v"(hi));
  return r;
}
union U8 { unsigned u[4]; short8 s; };

// ---------- x: f32 -> bf16 cast ---------------------------------------------
__global__ __launch_bounds__(256) void cvt_f32_bf16(const float* __restrict__ in,
                                                    short* __restrict__ out) {
  const int i = blockIdx.x * 256 + threadIdx.x;  // one short8 per thread
  float4 a = ((const float4*)in)[i * 2];
  float4 b = ((const float4*)in)[i * 2 + 1];
  short8 s;
  s[0] = f2bf(a.x); s[1] = f2bf(a.y); s[2] = f2bf(a.z); s[3] = f2bf(a.w);
  s[4] = f2bf(b.x); s[5] = f2bf(b.y); s[6] = f2bf(b.z); s[7] = f2bf(b.w);
  ((short8*)out)[i] = s;
}

// ---------- transpose + convert: out[c][r] = bf16(in[r][c]) ----------------
__global__ __launch_bounds__(256) void transpose_cvt(const float* __restrict__ in,
                                                     short* __restrict__ out,
                                                     int R, int C) {
  __shared__ float tile[32][33];
  const int c0 = blockIdx.x * 32, r0 = blockIdx.y * 32;
  const int tx = threadIdx.x & 31, ty = threadIdx.x >> 5;
#pragma unroll
  for (int i = 0; i < 32; i += 8)
    tile[ty + i][tx] = in[(size_t)(r0 + ty + i) * C + c0 + tx];
  __syncthreads();
#pragma unroll
  for (int i = 0; i < 32; i += 8)
    out[(size_t)(c0 + ty + i) * R + r0 + tx] = f2bf(tile[tx][ty + i]);
}

// ---------- 128x128 MFMA GEMM, BK=32, 4 waves, 2-phase gload_lds dbuf ------
// A[M][K] bf16; BT[n][k] bf16. Linear LDS [128][32] per buffer (m97 recipe).
// Prefetch tile t+1 issued BEFORE compute of tile t; __syncthreads' vmcnt(0)
// drain at iteration end gives one-tile overlap (T3 minimum 2-phase).
// EPI 0: scatter qkv to Q (pre-scaled by kQSc), K, V^T.  EPI 1: +bias, f32.
template <int EPI>
__global__ __launch_bounds__(256) void gemm_tile(const short* __restrict__ A,
                                                 const short* __restrict__ BT,
                                                 int Kd,
                                                 short* __restrict__ Qb,
                                                 short* __restrict__ Kb,
                                                 short* __restrict__ VTb,
                                                 const float* __restrict__ bias,
                                                 float* __restrict__ outF) {
  __shared__ short As[2][128 * 32];
  __shared__ short Bs[2][128 * 32];

  const int tid  = threadIdx.x;
  const int lane = tid & 63, w = tid >> 6;
  const int L = lane & 15, g = lane >> 4;
  const int wr = w >> 1, wc = w & 1;
  const int m0 = blockIdx.x * 128, n0 = blockIdx.y * 128;

  const int r4 = lane >> 2;        // row within 16-row chunk
  const int c8 = (lane & 3) * 8;   // k-col (shorts)

  auto stage = [&](int buf, int k0) {
#pragma unroll
    for (int c = 0; c < 2; ++c) {
      const short* ag = A  + (size_t)(m0 + w * 32 + c * 16 + r4) * Kd + k0 + c8;
      const short* bg = BT + (size_t)(n0 + w * 32 + c * 16 + r4) * Kd + k0 + c8;
      __builtin_amdgcn_global_load_lds((gvoid_p)ag, (lvoid_p)&As[buf][(w * 2 + c) * 512], 16, 0, 0);
      __builtin_amdgcn_global_load_lds((gvoid_p)bg, (lvoid_p)&Bs[buf][(w * 2 + c) * 512], 16, 0, 0);
    }
  };

  f32x4 acc[4][4] = {};

  stage(0, 0);
  __syncthreads();  // vmcnt(0) drain: tile 0 ready

  const int NT = Kd / 32;
  for (int t = 0; t < NT; ++t) {
    const int cur = t & 1;
    if (t + 1 < NT) stage(cur ^ 1, (t + 1) * 32);  // in flight during compute

    short8 af[4], bfr[4];
#pragma unroll
    for (int mi = 0; mi < 4; ++mi)
      af[mi] = *(const short8*)&As[cur][(wr * 64 + mi * 16 + L) * 32 + g * 8];
#pragma unroll
    for (int ni = 0; ni < 4; ++ni)
      bfr[ni] = *(const short8*)&Bs[cur][(wc * 64 + ni * 16 + L) * 32 + g * 8];
#pragma unroll
    for (int mi = 0; mi < 4; ++mi)
#pragma unroll
      for (int ni = 0; ni < 4; ++ni)
        acc[mi][ni] = MFMA_B16(af[mi], bfr[ni], acc[mi][ni]);

    __syncthreads();  // drains vmcnt (prefetch landed) + lgkm; reuse-safe
  }

  if (EPI == 0) {
    const int t3 = n0 / kDim;  // 0:Q 1:K 2:V (uniform per block; 768 = 6*128)
#pragma unroll
    for (int mi = 0; mi < 4; ++mi) {
#pragma unroll
      for (int ni = 0; ni < 4; ++ni) {
        const int gcol = n0 + wc * 64 + ni * 16 + L;
        const int hd = gcol % kDim;
        const int h = hd >> 6, d = hd & 63;
        if (t3 == 2) {  // V^T: 4 r-values are contiguous seq -> one 8B store
          const int grow = m0 + wr * 64 + mi * 16 + 4 * g;
          const int b = grow >> 10, seq = grow & 1023;
          const int bh = b * kHeads + h;
          uint2 d2;
          d2.x = cvt_pk_bf16(acc[mi][ni][0], acc[mi][ni][1]);
          d2.y = cvt_pk_bf16(acc[mi][ni][2], acc[mi][ni][3]);
          *(uint2*)&VTb[((size_t)bh * 64 + d) * kSeq + seq] = d2;
        } else {
#pragma unroll
          for (int r = 0; r < 4; ++r) {
            const int grow = m0 + wr * 64 + mi * 16 + 4 * g + r;  // b*1024+seq
            const int b = grow >> 10, seq = grow & 1023;
            const int bh = b * kHeads + h;
            if (t3 == 0) Qb[((size_t)bh * kSeq + seq) * 64 + d] = f2bf(acc[mi][ni][r] * kQSc);
            else         Kb[((size_t)bh * kSeq + seq) * 64 + d] = f2bf(acc[mi][ni][r]);
          }
        }
      }
    }
  } else {
#pragma unroll
    for (int ni = 0; ni < 4; ++ni) {
      const int gcol = n0 + wc * 64 + ni * 16 + L;
      const float bv = bias[gcol];
#pragma unroll
      for (int mi = 0; mi < 4; ++mi) {
#pragma unroll
        for (int r = 0; r < 4; ++r) {
          const int grow = m0 + wr * 64 + mi * 16 + 4 * g + r;
          outF[(size_t)grow * kDim + gcol] = acc[mi][ni][r] + bv;
        }
      }
    }
  }
}

// ---------- flash attention v4 (swapped QK^T, k-permuted PV, P in regs) ----
// 1D grid 768: id%8 == bh%8 -> per-bh K/V stays XCD-L2-resident.
// S^T = mfma(K,Q): lane(L,g) holds S[key=nf*16+4g+r][query=L].
// k-perm pi(g*8+j) = (j>>2)*16 + 4g + (j&3) applied to BOTH PV operands:
//   P A-frag = lane-local pack of p[nf][r] (8 cvt_pk, zero LDS traffic);
//   V B-frag = 4x ds_read_b64 at key offsets {4g,16+4g,32+4g,48+4g}.
__global__ __launch_bounds__(256) void attn_kernel(const short* __restrict__ Qb,
                                                   const short* __restrict__ Kb,
                                                   const short* __restrict__ VTb,
                                                   short* __restrict__ AO) {
  __shared__ short Ks[2][64 * 72];   // [key][d]
  __shared__ short VTs[2][64 * 72];  // [d][key]

  const int tid  = threadIdx.x;
  const int lane = tid & 63, w = tid >> 6;
  const int L = lane & 15, g = lane >> 4;
  const int id = blockIdx.x;
  const int bh = id % 96, qc = id / 96;
  const int q0 = qc * 128 + w * 32;

  const short* Qbase = Qb  + (size_t)bh * kSeq * 64;
  const short* Kbase = Kb  + (size_t)bh * kSeq * 64;
  const short* Vbase = VTb + (size_t)bh * 64 * kSeq;

  short8 qf[2][2];  // Q (pre-scaled by kQSc) as B-operand, resident in regs
#pragma unroll
  for (int qh = 0; qh < 2; ++qh) {
    const short* qp = Qbase + (size_t)(q0 + qh * 16 + L) * 64 + g * 8;
    qf[qh][0] = *(const short8*)qp;
    qf[qh][1] = *(const short8*)(qp + 32);
  }

  f32x4 o[2][4] = {};
  float m_[2] = {-1e30f, -1e30f};
  float l_[2] = {0.f, 0.f};

  const int srow = tid >> 2, sc0 = (tid & 3) * 16;  // staging: 16 elems/thread

  {  // prologue: stage tile 0
    const short* ksrc = Kbase + (size_t)srow * 64 + sc0;
    const short* vsrc = Vbase + (size_t)srow * kSeq + sc0;
    uint4 k0 = ((const uint4*)ksrc)[0], k1 = ((const uint4*)ksrc)[1];
    uint4 v0 = ((const uint4*)vsrc)[0], v1 = ((const uint4*)vsrc)[1];
    *(uint4*)&Ks[0][srow * 72 + sc0]      = k0;
    *(uint4*)&Ks[0][srow * 72 + sc0 + 8]  = k1;
    *(uint4*)&VTs[0][srow * 72 + sc0]     = v0;
    *(uint4*)&VTs[0][srow * 72 + sc0 + 8] = v1;
  }
  __syncthreads();

  for (int t = 0; t < kSeq / 64; ++t) {
    const int cur = t & 1;
    const bool pf = (t + 1 < kSeq / 64);

    // ---- issue next-tile loads early (T14 async split) ----
    uint4 kr0, kr1, vr0, vr1;
    if (pf) {
      const int kv1 = (t + 1) * 64;
      const short* ksrc = Kbase + (size_t)(kv1 + srow) * 64 + sc0;
      const short* vsrc = Vbase + (size_t)srow * kSeq + kv1 + sc0;
      kr0 = ((const uint4*)ksrc)[0]; kr1 = ((const uint4*)ksrc)[1];
      vr0 = ((const uint4*)vsrc)[0]; vr1 = ((const uint4*)vsrc)[1];
    }

    // ---- K fragments (A-operand), shared across both q-halves ----
    short8 kf[4][2];
#pragma unroll
    for (int nf = 0; nf < 4; ++nf) {
      const short* kp = &Ks[cur][(nf * 16 + L) * 72 + g * 8];
      kf[nf][0] = *(const short8*)kp;
      kf[nf][1] = *(const short8*)(kp + 32);
    }

    short8 pa[2][2];
#pragma unroll
    for (int qh = 0; qh < 2; ++qh) {
      // ---- S^T = K @ Q^T: lane holds S[key=nf*16+4g+r][query=L] ----
      f32x4 s[4];
#pragma unroll
      for (int nf = 0; nf < 4; ++nf) {
        f32x4 z = {};
        z = MFMA_B16(kf[nf][0], qf[qh][0], z);
        s[nf] = MFMA_B16(kf[nf][1], qf[qh][1], z);
      }
      // ---- row max: 15 in-reg + cross-g reduce (2 shfl) ----
      float x0 = fmaxf(fmaxf(s[0][0], s[0][1]), fmaxf(s[0][2], s[0][3]));
      float x1 = fmaxf(fmaxf(s[1][0], s[1][1]), fmaxf(s[1][2], s[1][3]));
      float x2 = fmaxf(fmaxf(s[2][0], s[2][1]), fmaxf(s[2][2], s[2][3]));
      float x3 = fmaxf(fmaxf(s[3][0], s[3][1]), fmaxf(s[3][2], s[3][3]));
      float mt = fmaxf(fmaxf(x0, x1), fmaxf(x2, x3));
      mt = fmaxf(mt, __shfl_xor(mt, 16, 64));
      mt = fmaxf(mt, __shfl_xor(mt, 32, 64));

      const bool grow = __any(mt > m_[qh] + 8.0f);  // defer-max (T13)
      const float mnew = grow ? fmaxf(m_[qh], mt) : m_[qh];

      // ---- p = exp2(s - m); P stays in registers (k-perm A-fragment) ----
      float rsum = 0.f;
#pragma unroll
      for (int nf = 0; nf < 4; ++nf) {
#pragma unroll
        for (int r = 0; r < 4; ++r) {
          const float p = __builtin_amdgcn_exp2f(s[nf][r] - mnew);
          s[nf][r] = p;
          rsum += p;
        }
      }
      rsum += __shfl_xor(rsum, 16, 64);
      rsum += __shfl_xor(rsum, 32, 64);

      U8 t0, t1;
      t0.u[0] = cvt_pk_bf16(s[0][0], s[0][1]);
      t0.u[1] = cvt_pk_bf16(s[0][2], s[0][3]);
      t0.u[2] = cvt_pk_bf16(s[1][0], s[1][1]);
      t0.u[3] = cvt_pk_bf16(s[1][2], s[1][3]);
      t1.u[0] = cvt_pk_bf16(s[2][0], s[2][1]);
      t1.u[1] = cvt_pk_bf16(s[2][2], s[2][3]);
      t1.u[2] = cvt_pk_bf16(s[3][0], s[3][1]);
      t1.u[3] = cvt_pk_bf16(s[3][2], s[3][3]);
      pa[qh][0] = t0.s;
      pa[qh][1] = t1.s;

      if (grow) {
        const float al = __builtin_amdgcn_exp2f(m_[qh] - mnew);
        m_[qh] = mnew;
        l_[qh] = l_[qh] * al + rsum;
        float alr[4];
#pragma unroll
        for (int r = 0; r < 4; ++r) alr[r] = __shfl(al, 4 * g + r, 64);
#pragma unroll
        for (int nf = 0; nf < 4; ++nf)
#pragma unroll
          for (int r = 0; r < 4; ++r) o[qh][nf][r] *= alr[r];
      } else {
        l_[qh] += rsum;
      }
    }

    // ---- O += P @ V with k-permuted B-fragments (4x b64 per nf) ----
#pragma unroll
    for (int nf = 0; nf < 4; ++nf) {
      const short* vrow = &VTs[cur][(nf * 16 + L) * 72];
      s16x4 a0 = *(const s16x4*)&vrow[4 * g];
      s16x4 a1 = *(const s16x4*)&vrow[16 + 4 * g];
      s16x4 a2 = *(const s16x4*)&vrow[32 + 4 * g];
      s16x4 a3 = *(const s16x4*)&vrow[48 + 4 * g];
      short8 vb0 = __builtin_shufflevector(a0, a1, 0, 1, 2, 3, 4, 5, 6, 7);
      short8 vb1 = __builtin_shufflevector(a2, a3, 0, 1, 2, 3, 4, 5, 6, 7);
#pragma unroll
      for (int qh = 0; qh < 2; ++qh) {
        o[qh][nf] = MFMA_B16(pa[qh][0], vb0, o[qh][nf]);
        o[qh][nf] = MFMA_B16(pa[qh][1], vb1, o[qh][nf]);
      }
    }

    // ---- write prefetched tile into other buffer; one barrier per tile ----
    if (pf) {
      *(uint4*)&Ks[cur ^ 1][srow * 72 + sc0]      = kr0;
      *(uint4*)&Ks[cur ^ 1][srow * 72 + sc0 + 8]  = kr1;
      *(uint4*)&VTs[cur ^ 1][srow * 72 + sc0]     = vr0;
      *(uint4*)&VTs[cur ^ 1][srow * 72 + sc0 + 8] = vr1;
    }
    __syncthreads();
  }

  // ---- finalize: O /= l (l gathered per output-row), store ----
  const int b = bh / kHeads, h = bh % kHeads;
#pragma unroll
  for (int qh = 0; qh < 2; ++qh) {
    float lq[4];
#pragma unroll
    for (int r = 0; r < 4; ++r) lq[r] = __shfl(l_[qh], 4 * g + r, 64);
    short* aop = AO + ((size_t)(b * kSeq) + q0 + qh * 16) * kDim + h * 64;
#pragma unroll
    for (int r = 0; r < 4; ++r) {
      const float inv = 1.0f / lq[r];
#pragma unroll
      for (int nf = 0; nf < 4; ++nf)
        aop[(size_t)(4 * g + r) * kDim + nf * 16 + L] = f2bf(o[qh][nf][r] * inv);
    }
  }
}

// ---------------------------------------------------------------------------
extern "C" void kernel_launch(void* const* d_in, const int* in_sizes, int n_in,
                              void* d_out, int out_size, void* d_ws, size_t ws_size,
                              hipStream_t stream) {
  const float* x     = (const float*)d_in[0];
  const float* w_in  = (const float*)d_in[1];
  const float* w_out = (const float*)d_in[2];
  const float* b_out = (const float*)d_in[3];
  float* out = (float*)d_out;

  // workspace (bf16 as short). xbf aliases AO: xbf dead before attn writes AO.
  short* WinT  = (short*)d_ws;                          // [2304][768]
  short* WoutT = WinT  + (size_t)2304 * 768;            // [768][768]
  short* Qb    = WoutT + (size_t)768 * 768;             // [96][1024][64]
  short* Kb    = Qb    + (size_t)96 * 1024 * 64;        // [96][1024][64]
  short* VTb   = Kb    + (size_t)96 * 1024 * 64;        // [96][64][1024]
  short* AO    = VTb   + (size_t)96 * 1024 * 64;        // [8192][768]
  short* xbf   = AO;                                    // alias (see above)

  cvt_f32_bf16<<<dim3(8192 * 768 / (256 * 8)), 256, 0, stream>>>(x, xbf);
  transpose_cvt<<<dim3(2304 / 32, 768 / 32), 256, 0, stream>>>(w_in, WinT, 768, 2304);
  transpose_cvt<<<dim3(768 / 32, 768 / 32), 256, 0, stream>>>(w_out, WoutT, 768, 768);

  gemm_tile<0><<<dim3(8192 / 128, 2304 / 128), 256, 0, stream>>>(
      xbf, WinT, 768, Qb, Kb, VTb, nullptr, nullptr);

  attn_kernel<<<dim3(768), 256, 0, stream>>>(Qb, Kb, VTb, AO);

  gemm_tile<1><<<dim3(8192 / 128, 768 / 128), 256, 0, stream>>>(
      AO, WoutT, 768, nullptr, nullptr, nullptr, b_out, out);
}

// Round 5
// 127.420 us; speedup vs baseline: 1.8054x; 1.0838x over previous
//
#include <hip/hip_runtime.h>

// ---------------------------------------------------------------------------
// MultiHeadedAttention: x[8,1024,768] @ w_in[768,2304] -> qkv -> 12-head attn
// (scale = 768^-0.5) -> concat -> @ w_out[768,768] + b_out. f32 in/out,
// bf16 MFMA internally. Attn: swapped QK^T + k-axis permutation (P in regs),
// lazy max-reduce + deferred l-reduce: no cross-lane ops on the common path.
// ---------------------------------------------------------------------------

using short8 = __attribute__((ext_vector_type(8))) short;  // 8 bf16 (4 VGPR)
using s16x4  = __attribute__((ext_vector_type(4))) short;  // 4 bf16 (b64)
using f32x4  = __attribute__((ext_vector_type(4))) float;  // MFMA acc

#define MFMA_B16(a, b, c) __builtin_amdgcn_mfma_f32_16x16x32_bf16((a), (b), (c), 0, 0, 0)

typedef const __attribute__((address_space(1))) void* gvoid_p;
typedef __attribute__((address_space(3))) void* lvoid_p;

constexpr int   kDim   = 768;
constexpr int   kHeads = 12;
constexpr int   kSeq   = 1024;
constexpr float kScale = 0.03608439182435161f;             // 768^-0.5 (full dim)
constexpr float kQSc   = kScale * 1.4426950408889634f;     // fold log2(e) into Q

__device__ __forceinline__ short f2bf(float f) {  // RNE f32 -> bf16 bits
  unsigned u = __float_as_uint(f);
  u += 0x7FFFu + ((u >> 16) & 1u);
  return (short)(u >> 16);
}
__device__ __forceinline__ unsigned cvt_pk_bf16(float lo, float hi) {
  unsigned r;
  asm("v_cvt_pk_bf16_f32 %0, %1, %2" : "=v"(r) : "v"(lo), "v"(hi));
  return r;
}
union U8 { unsigned u[4]; short8 s; };

// ---------- x: f32 -> bf16 cast ---------------------------------------------
__global__ __launch_bounds__(256) void cvt_f32_bf16(const float* __restrict__ in,
                                                    short* __restrict__ out) {
  const int i = blockIdx.x * 256 + threadIdx.x;  // one short8 per thread
  float4 a = ((const float4*)in)[i * 2];
  float4 b = ((const float4*)in)[i * 2 + 1];
  short8 s;
  s[0] = f2bf(a.x); s[1] = f2bf(a.y); s[2] = f2bf(a.z); s[3] = f2bf(a.w);
  s[4] = f2bf(b.x); s[5] = f2bf(b.y); s[6] = f2bf(b.z); s[7] = f2bf(b.w);
  ((short8*)out)[i] = s;
}

// ---------- transpose + convert: out[c][r] = bf16(in[r][c]) ----------------
__global__ __launch_bounds__(256) void transpose_cvt(const float* __restrict__ in,
                                                     short* __restrict__ out,
                                                     int R, int C) {
  __shared__ float tile[32][33];
  const int c0 = blockIdx.x * 32, r0 = blockIdx.y * 32;
  const int tx = threadIdx.x & 31, ty = threadIdx.x >> 5;
#pragma unroll
  for (int i = 0; i < 32; i += 8)
    tile[ty + i][tx] = in[(size_t)(r0 + ty + i) * C + c0 + tx];
  __syncthreads();
#pragma unroll
  for (int i = 0; i < 32; i += 8)
    out[(size_t)(c0 + ty + i) * R + r0 + tx] = f2bf(tile[tx][ty + i]);
}

// ---------- 128x128 MFMA GEMM, BK=32, 4 waves, 2-phase gload_lds dbuf ------
template <int EPI>
__global__ __launch_bounds__(256) void gemm_tile(const short* __restrict__ A,
                                                 const short* __restrict__ BT,
                                                 int Kd,
                                                 short* __restrict__ Qb,
                                                 short* __restrict__ Kb,
                                                 short* __restrict__ VTb,
                                                 const float* __restrict__ bias,
                                                 float* __restrict__ outF) {
  __shared__ short As[2][128 * 32];
  __shared__ short Bs[2][128 * 32];

  const int tid  = threadIdx.x;
  const int lane = tid & 63, w = tid >> 6;
  const int L = lane & 15, g = lane >> 4;
  const int wr = w >> 1, wc = w & 1;
  const int m0 = blockIdx.x * 128, n0 = blockIdx.y * 128;

  const int r4 = lane >> 2;        // row within 16-row chunk
  const int c8 = (lane & 3) * 8;   // k-col (shorts)

  auto stage = [&](int buf, int k0) {
#pragma unroll
    for (int c = 0; c < 2; ++c) {
      const short* ag = A  + (size_t)(m0 + w * 32 + c * 16 + r4) * Kd + k0 + c8;
      const short* bg = BT + (size_t)(n0 + w * 32 + c * 16 + r4) * Kd + k0 + c8;
      __builtin_amdgcn_global_load_lds((gvoid_p)ag, (lvoid_p)&As[buf][(w * 2 + c) * 512], 16, 0, 0);
      __builtin_amdgcn_global_load_lds((gvoid_p)bg, (lvoid_p)&Bs[buf][(w * 2 + c) * 512], 16, 0, 0);
    }
  };

  f32x4 acc[4][4] = {};

  stage(0, 0);
  __syncthreads();  // vmcnt(0) drain: tile 0 ready

  const int NT = Kd / 32;
  for (int t = 0; t < NT; ++t) {
    const int cur = t & 1;
    if (t + 1 < NT) stage(cur ^ 1, (t + 1) * 32);  // in flight during compute

    short8 af[4], bfr[4];
#pragma unroll
    for (int mi = 0; mi < 4; ++mi)
      af[mi] = *(const short8*)&As[cur][(wr * 64 + mi * 16 + L) * 32 + g * 8];
#pragma unroll
    for (int ni = 0; ni < 4; ++ni)
      bfr[ni] = *(const short8*)&Bs[cur][(wc * 64 + ni * 16 + L) * 32 + g * 8];
#pragma unroll
    for (int mi = 0; mi < 4; ++mi)
#pragma unroll
      for (int ni = 0; ni < 4; ++ni)
        acc[mi][ni] = MFMA_B16(af[mi], bfr[ni], acc[mi][ni]);

    __syncthreads();  // drains vmcnt (prefetch landed) + lgkm; reuse-safe
  }

  if (EPI == 0) {
    const int t3 = n0 / kDim;  // 0:Q 1:K 2:V (uniform per block; 768 = 6*128)
#pragma unroll
    for (int mi = 0; mi < 4; ++mi) {
#pragma unroll
      for (int ni = 0; ni < 4; ++ni) {
        const int gcol = n0 + wc * 64 + ni * 16 + L;
        const int hd = gcol % kDim;
        const int h = hd >> 6, d = hd & 63;
        if (t3 == 2) {  // V^T: 4 r-values are contiguous seq -> one 8B store
          const int grow = m0 + wr * 64 + mi * 16 + 4 * g;
          const int b = grow >> 10, seq = grow & 1023;
          const int bh = b * kHeads + h;
          uint2 d2;
          d2.x = cvt_pk_bf16(acc[mi][ni][0], acc[mi][ni][1]);
          d2.y = cvt_pk_bf16(acc[mi][ni][2], acc[mi][ni][3]);
          *(uint2*)&VTb[((size_t)bh * 64 + d) * kSeq + seq] = d2;
        } else {
#pragma unroll
          for (int r = 0; r < 4; ++r) {
            const int grow = m0 + wr * 64 + mi * 16 + 4 * g + r;  // b*1024+seq
            const int b = grow >> 10, seq = grow & 1023;
            const int bh = b * kHeads + h;
            if (t3 == 0) Qb[((size_t)bh * kSeq + seq) * 64 + d] = f2bf(acc[mi][ni][r] * kQSc);
            else         Kb[((size_t)bh * kSeq + seq) * 64 + d] = f2bf(acc[mi][ni][r]);
          }
        }
      }
    }
  } else {
#pragma unroll
    for (int ni = 0; ni < 4; ++ni) {
      const int gcol = n0 + wc * 64 + ni * 16 + L;
      const float bv = bias[gcol];
#pragma unroll
      for (int mi = 0; mi < 4; ++mi) {
#pragma unroll
        for (int r = 0; r < 4; ++r) {
          const int grow = m0 + wr * 64 + mi * 16 + 4 * g + r;
          outF[(size_t)grow * kDim + gcol] = acc[mi][ni][r] + bv;
        }
      }
    }
  }
}

// ---------- flash attention v5 ----------------------------------------------
// Swapped QK^T + k-perm PV (P in regs). NEW: (a) lazy max-reduce — defer-max
// test uses UNREDUCED per-lane maxima via __any (vcc, no LDS); the 2 max-shfls
// run only in the rare grow branch. (b) l_ kept as per-lane partial, reduced
// once at finalize (removes 2 shfls/tile-qh). (c) V B-frags hoisted next to
// K-frags so their ds latency hides under softmax. (d) setprio around MFMAs.
__global__ __launch_bounds__(256) void attn_kernel(const short* __restrict__ Qb,
                                                   const short* __restrict__ Kb,
                                                   const short* __restrict__ VTb,
                                                   short* __restrict__ AO) {
  __shared__ short Ks[2][64 * 72];   // [key][d]
  __shared__ short VTs[2][64 * 72];  // [d][key]

  const int tid  = threadIdx.x;
  const int lane = tid & 63, w = tid >> 6;
  const int L = lane & 15, g = lane >> 4;
  const int id = blockIdx.x;
  const int bh = id % 96, qc = id / 96;
  const int q0 = qc * 128 + w * 32;

  const short* Qbase = Qb  + (size_t)bh * kSeq * 64;
  const short* Kbase = Kb  + (size_t)bh * kSeq * 64;
  const short* Vbase = VTb + (size_t)bh * 64 * kSeq;

  short8 qf[2][2];  // Q (pre-scaled by kQSc) as B-operand, resident in regs
#pragma unroll
  for (int qh = 0; qh < 2; ++qh) {
    const short* qp = Qbase + (size_t)(q0 + qh * 16 + L) * 64 + g * 8;
    qf[qh][0] = *(const short8*)qp;
    qf[qh][1] = *(const short8*)(qp + 32);
  }

  f32x4 o[2][4] = {};
  float m_[2] = {-1e30f, -1e30f};  // per-query running max (replicated over g)
  float l_[2] = {0.f, 0.f};        // per-LANE partial sum (reduced at end)

  const int srow = tid >> 2, sc0 = (tid & 3) * 16;  // staging: 16 elems/thread

  {  // prologue: stage tile 0
    const short* ksrc = Kbase + (size_t)srow * 64 + sc0;
    const short* vsrc = Vbase + (size_t)srow * kSeq + sc0;
    uint4 k0 = ((const uint4*)ksrc)[0], k1 = ((const uint4*)ksrc)[1];
    uint4 v0 = ((const uint4*)vsrc)[0], v1 = ((const uint4*)vsrc)[1];
    *(uint4*)&Ks[0][srow * 72 + sc0]      = k0;
    *(uint4*)&Ks[0][srow * 72 + sc0 + 8]  = k1;
    *(uint4*)&VTs[0][srow * 72 + sc0]     = v0;
    *(uint4*)&VTs[0][srow * 72 + sc0 + 8] = v1;
  }
  __syncthreads();

  for (int t = 0; t < kSeq / 64; ++t) {
    const int cur = t & 1;
    const bool pf = (t + 1 < kSeq / 64);

    // ---- issue next-tile loads early (T14 async split) ----
    uint4 kr0, kr1, vr0, vr1;
    if (pf) {
      const int kv1 = (t + 1) * 64;
      const short* ksrc = Kbase + (size_t)(kv1 + srow) * 64 + sc0;
      const short* vsrc = Vbase + (size_t)srow * kSeq + kv1 + sc0;
      kr0 = ((const uint4*)ksrc)[0]; kr1 = ((const uint4*)ksrc)[1];
      vr0 = ((const uint4*)vsrc)[0]; vr1 = ((const uint4*)vsrc)[1];
    }

    // ---- K fragments (A-operand) + V fragments (k-perm B-operand) ----
    short8 kf[4][2];
#pragma unroll
    for (int nf = 0; nf < 4; ++nf) {
      const short* kp = &Ks[cur][(nf * 16 + L) * 72 + g * 8];
      kf[nf][0] = *(const short8*)kp;
      kf[nf][1] = *(const short8*)(kp + 32);
    }
    short8 vb[4][2];  // hoisted: latency hides under softmax below
#pragma unroll
    for (int nf = 0; nf < 4; ++nf) {
      const short* vrow = &VTs[cur][(nf * 16 + L) * 72];
      s16x4 a0 = *(const s16x4*)&vrow[4 * g];
      s16x4 a1 = *(const s16x4*)&vrow[16 + 4 * g];
      s16x4 a2 = *(const s16x4*)&vrow[32 + 4 * g];
      s16x4 a3 = *(const s16x4*)&vrow[48 + 4 * g];
      vb[nf][0] = __builtin_shufflevector(a0, a1, 0, 1, 2, 3, 4, 5, 6, 7);
      vb[nf][1] = __builtin_shufflevector(a2, a3, 0, 1, 2, 3, 4, 5, 6, 7);
    }

    short8 pa[2][2];
#pragma unroll
    for (int qh = 0; qh < 2; ++qh) {
      // ---- S^T = K @ Q^T: lane holds S[key=nf*16+4g+r][query=L] ----
      f32x4 s[4];
      __builtin_amdgcn_s_setprio(1);
#pragma unroll
      for (int nf = 0; nf < 4; ++nf) {
        f32x4 z = {};
        z = MFMA_B16(kf[nf][0], qf[qh][0], z);
        s[nf] = MFMA_B16(kf[nf][1], qf[qh][1], z);
      }
      __builtin_amdgcn_s_setprio(0);

      // ---- lazy defer-max: per-lane max only; no cross-lane on common path
      float x0 = fmaxf(fmaxf(s[0][0], s[0][1]), fmaxf(s[0][2], s[0][3]));
      float x1 = fmaxf(fmaxf(s[1][0], s[1][1]), fmaxf(s[1][2], s[1][3]));
      float x2 = fmaxf(fmaxf(s[2][0], s[2][1]), fmaxf(s[2][2], s[2][3]));
      float x3 = fmaxf(fmaxf(s[3][0], s[3][1]), fmaxf(s[3][2], s[3][3]));
      const float mt4 = fmaxf(fmaxf(x0, x1), fmaxf(x2, x3));

      if (__any(mt4 > m_[qh] + 8.0f)) {  // wave-uniform branch (rare)
        float mt = fmaxf(mt4, __shfl_xor(mt4, 16, 64));
        mt = fmaxf(mt, __shfl_xor(mt, 32, 64));          // per-query true max
        const float mnew = fmaxf(m_[qh], mt);
        const float al = __builtin_amdgcn_exp2f(m_[qh] - mnew);
        m_[qh] = mnew;
        l_[qh] *= al;  // per-lane partial: al is query-uniform across g
        float alr[4];
#pragma unroll
        for (int r = 0; r < 4; ++r) alr[r] = __shfl(al, 4 * g + r, 64);
#pragma unroll
        for (int nf = 0; nf < 4; ++nf)
#pragma unroll
          for (int r = 0; r < 4; ++r) o[qh][nf][r] *= alr[r];
      }

      // ---- p = exp2(s - m); lane-local sum; P packed in regs ----
      float rsum = 0.f;
#pragma unroll
      for (int nf = 0; nf < 4; ++nf) {
#pragma unroll
        for (int r = 0; r < 4; ++r) {
          const float p = __builtin_amdgcn_exp2f(s[nf][r] - m_[qh]);
          s[nf][r] = p;
          rsum += p;
        }
      }
      l_[qh] += rsum;  // per-lane partial

      U8 t0, t1;
      t0.u[0] = cvt_pk_bf16(s[0][0], s[0][1]);
      t0.u[1] = cvt_pk_bf16(s[0][2], s[0][3]);
      t0.u[2] = cvt_pk_bf16(s[1][0], s[1][1]);
      t0.u[3] = cvt_pk_bf16(s[1][2], s[1][3]);
      t1.u[0] = cvt_pk_bf16(s[2][0], s[2][1]);
      t1.u[1] = cvt_pk_bf16(s[2][2], s[2][3]);
      t1.u[2] = cvt_pk_bf16(s[3][0], s[3][1]);
      t1.u[3] = cvt_pk_bf16(s[3][2], s[3][3]);
      pa[qh][0] = t0.s;
      pa[qh][1] = t1.s;
    }

    // ---- O += P @ V ----
    __builtin_amdgcn_s_setprio(1);
#pragma unroll
    for (int nf = 0; nf < 4; ++nf) {
#pragma unroll
      for (int qh = 0; qh < 2; ++qh) {
        o[qh][nf] = MFMA_B16(pa[qh][0], vb[nf][0], o[qh][nf]);
        o[qh][nf] = MFMA_B16(pa[qh][1], vb[nf][1], o[qh][nf]);
      }
    }
    __builtin_amdgcn_s_setprio(0);

    // ---- write prefetched tile into other buffer; one barrier per tile ----
    if (pf) {
      *(uint4*)&Ks[cur ^ 1][srow * 72 + sc0]      = kr0;
      *(uint4*)&Ks[cur ^ 1][srow * 72 + sc0 + 8]  = kr1;
      *(uint4*)&VTs[cur ^ 1][srow * 72 + sc0]     = vr0;
      *(uint4*)&VTs[cur ^ 1][srow * 72 + sc0 + 8] = vr1;
    }
    __syncthreads();
  }

  // ---- finalize: reduce l across g-groups ONCE, O /= l, store ----
  const int b = bh / kHeads, h = bh % kHeads;
#pragma unroll
  for (int qh = 0; qh < 2; ++qh) {
    float ls = l_[qh] + __shfl_xor(l_[qh], 16, 64);
    ls += __shfl_xor(ls, 32, 64);  // full per-query sum
    float lq[4];
#pragma unroll
    for (int r = 0; r < 4; ++r) lq[r] = __shfl(ls, 4 * g + r, 64);
    short* aop = AO + ((size_t)(b * kSeq) + q0 + qh * 16) * kDim + h * 64;
#pragma unroll
    for (int r = 0; r < 4; ++r) {
      const float inv = 1.0f / lq[r];
#pragma unroll
      for (int nf = 0; nf < 4; ++nf)
        aop[(size_t)(4 * g + r) * kDim + nf * 16 + L] = f2bf(o[qh][nf][r] * inv);
    }
  }
}

// ---------------------------------------------------------------------------
extern "C" void kernel_launch(void* const* d_in, const int* in_sizes, int n_in,
                              void* d_out, int out_size, void* d_ws, size_t ws_size,
                              hipStream_t stream) {
  const float* x     = (const float*)d_in[0];
  const float* w_in  = (const float*)d_in[1];
  const float* w_out = (const float*)d_in[2];
  const float* b_out = (const float*)d_in[3];
  float* out = (float*)d_out;

  // workspace (bf16 as short). xbf aliases AO: xbf dead before attn writes AO.
  short* WinT  = (short*)d_ws;                          // [2304][768]
  short* WoutT = WinT  + (size_t)2304 * 768;            // [768][768]
  short* Qb    = WoutT + (size_t)768 * 768;             // [96][1024][64]
  short* Kb    = Qb    + (size_t)96 * 1024 * 64;        // [96][1024][64]
  short* VTb   = Kb    + (size_t)96 * 1024 * 64;        // [96][64][1024]
  short* AO    = VTb   + (size_t)96 * 1024 * 64;        // [8192][768]
  short* xbf   = AO;                                    // alias (see above)

  cvt_f32_bf16<<<dim3(8192 * 768 / (256 * 8)), 256, 0, stream>>>(x, xbf);
  transpose_cvt<<<dim3(2304 / 32, 768 / 32), 256, 0, stream>>>(w_in, WinT, 768, 2304);
  transpose_cvt<<<dim3(768 / 32, 768 / 32), 256, 0, stream>>>(w_out, WoutT, 768, 768);

  gemm_tile<0><<<dim3(8192 / 128, 2304 / 128), 256, 0, stream>>>(
      xbf, WinT, 768, Qb, Kb, VTb, nullptr, nullptr);

  attn_kernel<<<dim3(768), 256, 0, stream>>>(Qb, Kb, VTb, AO);

  gemm_tile<1><<<dim3(8192 / 128, 768 / 128), 256, 0, stream>>>(
      AO, WoutT, 768, nullptr, nullptr, nullptr, b_out, out);
}